// Round 1
// baseline (1396.726 us; speedup 1.0000x reference)
//
#include <hip/hip_runtime.h>

// EfConv forward, restructured:
//   t = node_feat @ W^T                      [N,64]   (kernel 1)
//   out[n,k,o] = b[o]                                  (kernel 2)
//   out[dst[e],k,o] += edge_feat[e,k]*t[src[e],o]      (kernel 3, atomics)
// This hoists the shared linear before aggregation (valid since the linear is
// along in_feats and aggregation is a plain sum), avoiding the 102MB agg
// intermediate and shrinking the GEMM by 8x.

#define FEATS 64
#define EDGE_DIM 8

// ---- Kernel 1: t[n][o] = sum_i nf[n][i] * W[o][i] ----
// 256 threads = 4 nodes/block. W staged transposed in LDS with +1 pad
// (sWt[i][o], stride 65) so the inner-product reads are conflict-free.
__global__ void __launch_bounds__(256) transform_kernel(
    const float* __restrict__ nf, const float* __restrict__ W,
    float* __restrict__ t, int n_nodes)
{
    __shared__ float sWt[FEATS * 65];
    __shared__ float srow[4][FEATS];
    const int tid = threadIdx.x;

    #pragma unroll
    for (int base = 0; base < FEATS * FEATS; base += 256) {
        int idx = base + tid;
        int o = idx >> 6;
        int i = idx & 63;
        sWt[i * 65 + o] = W[idx];
    }

    const int r = tid >> 6;      // node within block (0..3)
    const int o = tid & 63;      // output feature
    const int node = blockIdx.x * 4 + r;
    if (node < n_nodes) srow[r][o] = nf[(long)node * FEATS + o];
    __syncthreads();

    if (node >= n_nodes) return;
    float sum = 0.f;
    #pragma unroll
    for (int i = 0; i < FEATS; i++)
        sum += srow[r][i] * sWt[i * 65 + o];
    t[(long)node * FEATS + o] = sum;
}

// ---- Kernel 2: out[n*512 + k*64 + o] = b[o], vectorized float4 ----
__global__ void __launch_bounds__(256) init_bias_kernel(
    const float4* __restrict__ b4, float4* __restrict__ out4, long total4)
{
    long i = (long)blockIdx.x * blockDim.x + threadIdx.x;
    if (i < total4) out4[i] = b4[i & 15];   // 64 floats of b = 16 float4s
}

// ---- Kernel 3: edge scatter with atomics ----
// 64 lanes per edge; lane = output feature o. 8 atomicAdds per lane (one per
// edge-feature slice k).
__global__ void __launch_bounds__(256) scatter_kernel(
    const float* __restrict__ t, const float* __restrict__ ef,
    const int* __restrict__ src, const int* __restrict__ dst,
    float* __restrict__ out, int n_edges)
{
    long gid = (long)blockIdx.x * blockDim.x + threadIdx.x;
    int e = (int)(gid >> 6);
    int o = (int)(gid & 63);
    if (e >= n_edges) return;

    const int s = src[e];   // wave-uniform (all 64 lanes same e) -> broadcast
    const int d = dst[e];
    const float tv = t[(long)s * FEATS + o];   // coalesced 256B per edge

    const float* efe = ef + (long)e * EDGE_DIM;
    float* outp = out + (long)d * (EDGE_DIM * FEATS) + o;
    #pragma unroll
    for (int k = 0; k < EDGE_DIM; k++) {
        atomicAdd(outp + k * FEATS, efe[k] * tv);
    }
}

extern "C" void kernel_launch(void* const* d_in, const int* in_sizes, int n_in,
                              void* d_out, int out_size, void* d_ws, size_t ws_size,
                              hipStream_t stream) {
    const float* node_feat = (const float*)d_in[0];
    const float* edge_feat = (const float*)d_in[1];
    const float* W         = (const float*)d_in[2];
    const float* b         = (const float*)d_in[3];
    const int*   src       = (const int*)d_in[4];
    const int*   dst       = (const int*)d_in[5];
    float* out = (float*)d_out;

    const int n_nodes = in_sizes[0] / FEATS;
    const int n_edges = in_sizes[4];

    float* t = (float*)d_ws;   // [n_nodes * 64] fp32 = 12.8 MB

    transform_kernel<<<(n_nodes + 3) / 4, 256, 0, stream>>>(node_feat, W, t, n_nodes);

    const long total4 = (long)n_nodes * (EDGE_DIM * FEATS) / 4;
    init_bias_kernel<<<(int)((total4 + 255) / 256), 256, 0, stream>>>(
        (const float4*)b, (float4*)out, total4);

    const long total_sc = (long)n_edges * 64;
    scatter_kernel<<<(int)((total_sc + 255) / 256), 256, 0, stream>>>(
        t, edge_feat, src, dst, out, n_edges);
}

// Round 2
// 333.135 us; speedup vs baseline: 4.1927x; 4.1927x over previous
//
#include <hip/hip_runtime.h>

// EfConv forward, CSR-based (no fp32 atomics):
//   1. t = node_feat @ W^T                             [N,64]
//   2. deg[d] = #edges with dst==d   (int atomics)
//   3. offsets = exclusive_scan(deg) (3-kernel scan)
//   4. permute: pos=cursor[dst[e]]++; src_s[pos]=src[e]; perm[pos]=e
//   5. aggregate: per node n (one wave, lanes=o):
//        out[n,k,o] = b[o] + sum_{j in row n} ef[perm[j],k] * t[src_s[j],o]
// Output written exactly once -> no init kernel, no fp32 atomics.

#define FEATS 64
#define EDGE_DIM 8

// ---- Kernel 1: t[n][o] = sum_i nf[n][i] * W[o][i] ----
__global__ void __launch_bounds__(256) transform_kernel(
    const float* __restrict__ nf, const float* __restrict__ W,
    float* __restrict__ t, int n_nodes)
{
    __shared__ float sWt[FEATS * 65];
    __shared__ float srow[4][FEATS];
    const int tid = threadIdx.x;

    #pragma unroll
    for (int base = 0; base < FEATS * FEATS; base += 256) {
        int idx = base + tid;
        int o = idx >> 6;
        int i = idx & 63;
        sWt[i * 65 + o] = W[idx];
    }

    const int r = tid >> 6;
    const int o = tid & 63;
    const int node = blockIdx.x * 4 + r;
    if (node < n_nodes) srow[r][o] = nf[(long)node * FEATS + o];
    __syncthreads();

    if (node >= n_nodes) return;
    float sum = 0.f;
    #pragma unroll
    for (int i = 0; i < FEATS; i++)
        sum += srow[r][i] * sWt[i * 65 + o];
    t[(long)node * FEATS + o] = sum;
}

// ---- Kernel 2: zero an int array ----
__global__ void __launch_bounds__(256) zero_kernel(int* __restrict__ p, int n)
{
    int i = blockIdx.x * 256 + threadIdx.x;
    if (i < n) p[i] = 0;
}

// ---- Kernel 3: histogram of dst ----
__global__ void __launch_bounds__(256) hist_kernel(
    const int* __restrict__ dst, int* __restrict__ deg, int n_edges)
{
    int e = blockIdx.x * 256 + threadIdx.x;
    if (e < n_edges) atomicAdd(&deg[dst[e]], 1);
}

// ---- Kernel 4a: per-block partial sums of deg ----
__global__ void __launch_bounds__(256) partials_kernel(
    const int* __restrict__ deg, int* __restrict__ partials, int n)
{
    __shared__ int s[256];
    int i = blockIdx.x * 256 + threadIdx.x;
    s[threadIdx.x] = (i < n) ? deg[i] : 0;
    __syncthreads();
    for (int off = 128; off > 0; off >>= 1) {
        if (threadIdx.x < off) s[threadIdx.x] += s[threadIdx.x + off];
        __syncthreads();
    }
    if (threadIdx.x == 0) partials[blockIdx.x] = s[0];
}

// ---- Kernel 4b: exclusive scan of partials (single block, nb <= 256) ----
__global__ void __launch_bounds__(256) scan_partials_kernel(
    const int* __restrict__ partials, int* __restrict__ pscan, int nb)
{
    __shared__ int s[256];
    int tid = threadIdx.x;
    s[tid] = (tid < nb) ? partials[tid] : 0;
    for (int off = 1; off < 256; off <<= 1) {
        __syncthreads();
        int x = (tid >= off) ? s[tid - off] : 0;
        __syncthreads();
        s[tid] += x;
    }
    __syncthreads();
    // exclusive
    pscan[tid] = (tid == 0) ? 0 : s[tid - 1];
}

// ---- Kernel 4c: block-local exclusive scan + add partial offset ----
__global__ void __launch_bounds__(256) scan_addback_kernel(
    const int* __restrict__ deg, const int* __restrict__ pscan,
    int* __restrict__ offsets, int* __restrict__ cursor,
    int n, int n_edges)
{
    __shared__ int s[256];
    int tid = threadIdx.x;
    int i = blockIdx.x * 256 + tid;
    int v = (i < n) ? deg[i] : 0;
    s[tid] = v;
    for (int off = 1; off < 256; off <<= 1) {
        __syncthreads();
        int x = (tid >= off) ? s[tid - off] : 0;
        __syncthreads();
        s[tid] += x;
    }
    __syncthreads();
    if (i < n) {
        int excl = pscan[blockIdx.x] + s[tid] - v;   // inclusive - self = exclusive
        offsets[i] = excl;
        cursor[i]  = excl;
    }
    if (blockIdx.x == 0 && tid == 0) offsets[n] = n_edges;
}

// ---- Kernel 5: permute edges into dst-sorted order ----
__global__ void __launch_bounds__(256) permute_kernel(
    const int* __restrict__ src, const int* __restrict__ dst,
    int* __restrict__ cursor, int* __restrict__ src_s, int* __restrict__ perm,
    int n_edges)
{
    int e = blockIdx.x * 256 + threadIdx.x;
    if (e >= n_edges) return;
    int pos = atomicAdd(&cursor[dst[e]], 1);
    src_s[pos] = src[e];
    perm[pos] = e;
}

// ---- Kernel 6: per-node aggregation (one wave per node, lanes = o) ----
__global__ void __launch_bounds__(256) aggregate_kernel(
    const float* __restrict__ t, const float* __restrict__ ef,
    const int* __restrict__ src_s, const int* __restrict__ perm,
    const int* __restrict__ offsets, const float* __restrict__ b,
    float* __restrict__ out, int n_nodes)
{
    int node = (blockIdx.x * 256 + threadIdx.x) >> 6;
    int o = threadIdx.x & 63;
    if (node >= n_nodes) return;

    int beg = offsets[node];
    int end = offsets[node + 1];
    float acc[EDGE_DIM];
    #pragma unroll
    for (int k = 0; k < EDGE_DIM; k++) acc[k] = 0.f;

    int j = beg;
    // 2-edge unroll for ILP (overlap the two gather chains)
    for (; j + 1 < end; j += 2) {
        int e0 = perm[j],     e1 = perm[j + 1];
        int s0 = src_s[j],    s1 = src_s[j + 1];
        float tv0 = t[(long)s0 * FEATS + o];
        float tv1 = t[(long)s1 * FEATS + o];
        const float4* p0 = (const float4*)(ef + (long)e0 * EDGE_DIM);
        const float4* p1 = (const float4*)(ef + (long)e1 * EDGE_DIM);
        float4 a0 = p0[0], a1 = p0[1];
        float4 c0 = p1[0], c1 = p1[1];
        acc[0] += a0.x * tv0; acc[1] += a0.y * tv0;
        acc[2] += a0.z * tv0; acc[3] += a0.w * tv0;
        acc[4] += a1.x * tv0; acc[5] += a1.y * tv0;
        acc[6] += a1.z * tv0; acc[7] += a1.w * tv0;
        acc[0] += c0.x * tv1; acc[1] += c0.y * tv1;
        acc[2] += c0.z * tv1; acc[3] += c0.w * tv1;
        acc[4] += c1.x * tv1; acc[5] += c1.y * tv1;
        acc[6] += c1.z * tv1; acc[7] += c1.w * tv1;
    }
    if (j < end) {
        int e0 = perm[j];
        int s0 = src_s[j];
        float tv0 = t[(long)s0 * FEATS + o];
        const float4* p0 = (const float4*)(ef + (long)e0 * EDGE_DIM);
        float4 a0 = p0[0], a1 = p0[1];
        acc[0] += a0.x * tv0; acc[1] += a0.y * tv0;
        acc[2] += a0.z * tv0; acc[3] += a0.w * tv0;
        acc[4] += a1.x * tv0; acc[5] += a1.y * tv0;
        acc[6] += a1.z * tv0; acc[7] += a1.w * tv0;
    }

    float bo = b[o];
    float* op = out + (long)node * (EDGE_DIM * FEATS) + o;
    #pragma unroll
    for (int k = 0; k < EDGE_DIM; k++)
        op[k * FEATS] = acc[k] + bo;
}

extern "C" void kernel_launch(void* const* d_in, const int* in_sizes, int n_in,
                              void* d_out, int out_size, void* d_ws, size_t ws_size,
                              hipStream_t stream) {
    const float* node_feat = (const float*)d_in[0];
    const float* edge_feat = (const float*)d_in[1];
    const float* W         = (const float*)d_in[2];
    const float* b         = (const float*)d_in[3];
    const int*   src       = (const int*)d_in[4];
    const int*   dst       = (const int*)d_in[5];
    float* out = (float*)d_out;

    const int n_nodes = in_sizes[0] / FEATS;
    const int n_edges = in_sizes[4];
    const int nb_nodes = (n_nodes + 255) / 256;      // blocks over nodes (<=256 required)
    const int nb_edges = (n_edges + 255) / 256;

    // workspace layout (4B units)
    int* w = (int*)d_ws;
    float* t      = (float*)w;                 // N*64
    int* deg      = w + (long)n_nodes * FEATS;         // N
    int* offsets  = deg + n_nodes;                     // N+1
    int* cursor   = offsets + n_nodes + 1;             // N
    int* partials = cursor + n_nodes;                  // 256
    int* pscan    = partials + 256;                    // 256
    int* src_s    = pscan + 256;                       // E
    int* perm     = src_s + n_edges;                   // E

    transform_kernel<<<(n_nodes + 3) / 4, 256, 0, stream>>>(node_feat, W, t, n_nodes);
    zero_kernel<<<nb_nodes, 256, 0, stream>>>(deg, n_nodes);
    hist_kernel<<<nb_edges, 256, 0, stream>>>(dst, deg, n_edges);
    partials_kernel<<<nb_nodes, 256, 0, stream>>>(deg, partials, n_nodes);
    scan_partials_kernel<<<1, 256, 0, stream>>>(partials, pscan, nb_nodes);
    scan_addback_kernel<<<nb_nodes, 256, 0, stream>>>(deg, pscan, offsets, cursor,
                                                      n_nodes, n_edges);
    permute_kernel<<<nb_edges, 256, 0, stream>>>(src, dst, cursor, src_s, perm, n_edges);

    const long total_ag = (long)n_nodes * 64;
    aggregate_kernel<<<(int)((total_ag + 255) / 256), 256, 0, stream>>>(
        t, edge_feat, src_s, perm, offsets, b, out, n_nodes);
}